// Round 2
// baseline (1083.600 us; speedup 1.0000x reference)
//
#include <hip/hip_runtime.h>
#include <math.h>

// Problem constants
#define NTOK   32768       // B*S = 4*8192
#define D      2048        // N_EMBED
#define E      64          // NUM_EXPERTS
#define TOPK   8
#define NC     128         // 64 router cols + 64 noise cols

// Tiling
#define TM     64          // tokens per block
#define BK     32          // K chunk
#define NBLK   (NTOK / TM) // 512
#define NKC    (D / BK)    // 64

// LDS layout (floats)
#define XS_OFF    0        // xs[BK][68] transposed x tile
#define XS_STR    68
#define WS_OFF    2176     // ws[BK][128]
#define WSK_OFF   6272     // wskip[BK]
#define LG_STR    132      // logits[64][132] reuses [0..8448) after K loop
#define SP_OFF    8448     // skip partials [128]
#define SMEM_FLOATS 8576

// near-tie flag threshold: fp32 worst-case dot error ~2e-4; 5x margin
#define TIE_EPS 1e-3f

__global__ __launch_bounds__(128, 2) void router_kernel(
    const float* __restrict__ x, const float* __restrict__ eps,
    const float* __restrict__ w_router, const float* __restrict__ b_router,
    const float* __restrict__ w_noise, const float* __restrict__ b_noise,
    const float* __restrict__ w_skip, const float* __restrict__ b_skip,
    float* __restrict__ out_router, float* __restrict__ out_idx,
    float* __restrict__ out_skip, int* __restrict__ flags, int cap)
{
    __shared__ float smem[SMEM_FLOATS];
    const int tid = threadIdx.x;
    const int tokBase = blockIdx.x * TM;

    const int c0 = (tid & 15) * 8;
    const int t0 = (tid >> 4) * 8;
    const int tS = tid & 63;
    const int half = tid >> 6;

    float acc[8][8];
#pragma unroll
    for (int a = 0; a < 8; ++a)
#pragma unroll
        for (int b = 0; b < 8; ++b) acc[a][b] = 0.f;
    float skipAcc = 0.f;

    float4 rx[4];
    float4 rw[8];
    float rwsk;

    auto loadChunk = [&](int kBase) {
#pragma unroll
        for (int r = 0; r < 4; ++r) {
            int f = tid + 128 * r;
            int token = f >> 3;
            int q = f & 7;
            rx[r] = *(const float4*)(x + (size_t)(tokBase + token) * D + kBase + q * 4);
        }
#pragma unroll
        for (int r = 0; r < 8; ++r) {
            int f = tid + 128 * r;
            int kk = f >> 5;
            int cq = f & 31;
            const float* src = (cq < 16)
                ? (w_router + (size_t)(kBase + kk) * E + cq * 4)
                : (w_noise  + (size_t)(kBase + kk) * E + (cq - 16) * 4);
            rw[r] = *(const float4*)src;
        }
        rwsk = w_skip[kBase + (tid & 31)];
    };

    auto storeChunk = [&]() {
#pragma unroll
        for (int r = 0; r < 4; ++r) {
            int f = tid + 128 * r;
            int token = f >> 3;
            int q = f & 7;
            smem[XS_OFF + (q * 4 + 0) * XS_STR + token] = rx[r].x;
            smem[XS_OFF + (q * 4 + 1) * XS_STR + token] = rx[r].y;
            smem[XS_OFF + (q * 4 + 2) * XS_STR + token] = rx[r].z;
            smem[XS_OFF + (q * 4 + 3) * XS_STR + token] = rx[r].w;
        }
#pragma unroll
        for (int r = 0; r < 8; ++r) {
            int f = tid + 128 * r;
            int kk = f >> 5;
            int cq = f & 31;
            *(float4*)&smem[WS_OFF + kk * NC + cq * 4] = rw[r];
        }
        if (tid < 32) smem[WSK_OFF + tid] = rwsk;
    };

    loadChunk(0);

    for (int kc = 0; kc < NKC; ++kc) {
        __syncthreads();
        storeChunk();
        __syncthreads();

        int kNext = (kc + 1 < NKC) ? (kc + 1) * BK : kc * BK;
        loadChunk(kNext);

#pragma unroll 4
        for (int kk = 0; kk < BK; ++kk) {
            float4 xa = *(float4*)&smem[XS_OFF + kk * XS_STR + t0];
            float4 xb = *(float4*)&smem[XS_OFF + kk * XS_STR + t0 + 4];
            float4 wa = *(float4*)&smem[WS_OFF + kk * NC + c0];
            float4 wb = *(float4*)&smem[WS_OFF + kk * NC + c0 + 4];
            float xv[8] = {xa.x, xa.y, xa.z, xa.w, xb.x, xb.y, xb.z, xb.w};
            float wv[8] = {wa.x, wa.y, wa.z, wa.w, wb.x, wb.y, wb.z, wb.w};
#pragma unroll
            for (int a = 0; a < 8; ++a)
#pragma unroll
                for (int b = 0; b < 8; ++b)
                    acc[a][b] = fmaf(xv[a], wv[b], acc[a][b]);
        }

#pragma unroll
        for (int kk = 0; kk < 16; ++kk) {
            int k2 = half * 16 + kk;
            skipAcc = fmaf(smem[XS_OFF + k2 * XS_STR + tS], smem[WSK_OFF + k2], skipAcc);
        }
    }

    __syncthreads();

#pragma unroll
    for (int a = 0; a < 8; ++a) {
        float4 v0 = make_float4(acc[a][0], acc[a][1], acc[a][2], acc[a][3]);
        float4 v1 = make_float4(acc[a][4], acc[a][5], acc[a][6], acc[a][7]);
        *(float4*)&smem[(t0 + a) * LG_STR + c0]     = v0;
        *(float4*)&smem[(t0 + a) * LG_STR + c0 + 4] = v1;
    }
    smem[SP_OFF + half * 64 + tS] = skipAcc;
    __syncthreads();

    if (tid < 64) {
        const int t = tid;
        const int tok = tokBase + t;
        float* row = &smem[t * LG_STR];

        float sv = smem[SP_OFF + t] + smem[SP_OFF + 64 + t] + b_skip[0];
        out_skip[tok] = 1.f / (1.f + expf(-sv));

#pragma unroll 4
        for (int e4 = 0; e4 < 16; ++e4) {
            float4 ep = *(const float4*)(eps + (size_t)tok * E + e4 * 4);
            float epv[4] = {ep.x, ep.y, ep.z, ep.w};
#pragma unroll
            for (int u = 0; u < 4; ++u) {
                int e = e4 * 4 + u;
                float lg = row[e] + b_router[e];
                float nl = row[64 + e] + b_noise[e];
                float sp = fmaxf(nl, 0.f) + log1pf(expf(-fabsf(nl)));
                row[e] = lg + epv[u] * sp;
            }
        }

        // top-9 (need 9th value for the membership-boundary gap check)
        float vals[9];
        int idxs[8];
        for (int p = 0; p < 9; ++p) {
            float best = -INFINITY;
            int bi = 0;
            for (int e = 0; e < 64; ++e) {
                float v = row[e];
                if (v > best) { best = v; bi = e; }
            }
            vals[p] = best;
            if (p < 8) idxs[p] = bi;
            row[bi] = -INFINITY;
        }

        // flag near-ties at any boundary affecting top-8 content/order
        float mg = 1e30f;
#pragma unroll
        for (int p = 0; p < 8; ++p) mg = fminf(mg, vals[p] - vals[p + 1]);
        if (mg < TIE_EPS) {
            int slot = atomicAdd(flags, 1);
            if (slot < cap) flags[2 + slot] = tok;
        }

        float m = vals[0];
        float g[8];
        float s = 0.f;
#pragma unroll
        for (int p = 0; p < 8; ++p) { g[p] = expf(vals[p] - m); s += g[p]; }
        float inv = 1.f / s;

        float* rrow = row + 64;
#pragma unroll
        for (int e4 = 0; e4 < 16; ++e4)
            *(float4*)&rrow[e4 * 4] = make_float4(0.f, 0.f, 0.f, 0.f);
#pragma unroll
        for (int p = 0; p < 8; ++p) rrow[idxs[p]] = g[p] * inv;
#pragma unroll
        for (int e4 = 0; e4 < 16; ++e4)
            *(float4*)(out_router + (size_t)tok * E + e4 * 4) = *(float4*)&rrow[e4 * 4];

        float4 i0 = make_float4((float)idxs[0], (float)idxs[1], (float)idxs[2], (float)idxs[3]);
        float4 i1 = make_float4((float)idxs[4], (float)idxs[5], (float)idxs[6], (float)idxs[7]);
        *(float4*)(out_idx + (size_t)tok * TOPK)     = i0;
        *(float4*)(out_idx + (size_t)tok * TOPK + 4) = i1;
    }
}

// f64 recompute for near-tie tokens: 256 threads = 64 experts x 2 matrices x 2 k-halves
__global__ __launch_bounds__(256) void fixup_kernel(
    const float* __restrict__ x, const float* __restrict__ eps,
    const float* __restrict__ w_router, const float* __restrict__ b_router,
    const float* __restrict__ w_noise, const float* __restrict__ b_noise,
    float* __restrict__ out_router, float* __restrict__ out_idx,
    const int* __restrict__ flags, int cap)
{
    __shared__ double red[256];
    __shared__ double noisy[64];
    const int tid = threadIdx.x;
    const int e  = tid & 63;
    const int m  = (tid >> 6) & 1;
    const int hf = tid >> 7;
    const float* w = m ? w_noise : w_router;

    int count = flags[0];
    if (count > cap) count = cap;

    for (int i = blockIdx.x; i < count; i += gridDim.x) {
        int tok = flags[2 + i];
        const float* xr = x + (size_t)tok * D;
        double part = 0.0;
        int k0 = hf * (D / 2);
        for (int k = k0; k < k0 + D / 2; k += 4) {
            float4 xv = *(const float4*)(xr + k);
            part += (double)xv.x * (double)w[(size_t)(k + 0) * E + e];
            part += (double)xv.y * (double)w[(size_t)(k + 1) * E + e];
            part += (double)xv.z * (double)w[(size_t)(k + 2) * E + e];
            part += (double)xv.w * (double)w[(size_t)(k + 3) * E + e];
        }
        red[tid] = part;
        __syncthreads();
        if (tid < 128) red[tid] = red[tid] + red[tid + 128];
        __syncthreads();
        if (tid < 64) {
            double lg = red[tid] + (double)b_router[tid];
            double nl = red[64 + tid] + (double)b_noise[tid];
            double sp = fmax(nl, 0.0) + log1p(exp(-fabs(nl)));
            noisy[tid] = lg + (double)eps[(size_t)tok * E + tid] * sp;
        }
        __syncthreads();
        if (tid == 0) {
            double tmp[64];
            for (int j = 0; j < 64; ++j) tmp[j] = noisy[j];
            double vals[8]; int idxs[8];
            for (int p = 0; p < 8; ++p) {
                double best = -1e300; int bi = 0;
                for (int j = 0; j < 64; ++j)
                    if (tmp[j] > best) { best = tmp[j]; bi = j; }
                vals[p] = best; idxs[p] = bi; tmp[bi] = -1e300;
            }
            double mx = vals[0], s = 0.0, g[8];
            for (int p = 0; p < 8; ++p) { g[p] = exp(vals[p] - mx); s += g[p]; }
            float row[64];
            for (int j = 0; j < 64; ++j) row[j] = 0.f;
            for (int p = 0; p < 8; ++p) row[idxs[p]] = (float)(g[p] / s);
            for (int j = 0; j < 64; ++j) out_router[(size_t)tok * E + j] = row[j];
            for (int p = 0; p < 8; ++p) out_idx[(size_t)tok * TOPK + p] = (float)idxs[p];
        }
        __syncthreads();
    }
}

extern "C" void kernel_launch(void* const* d_in, const int* in_sizes, int n_in,
                              void* d_out, int out_size, void* d_ws, size_t ws_size,
                              hipStream_t stream) {
    const float* x        = (const float*)d_in[0];
    const float* eps      = (const float*)d_in[1];
    const float* w_router = (const float*)d_in[2];
    const float* b_router = (const float*)d_in[3];
    const float* w_noise  = (const float*)d_in[4];
    const float* b_noise  = (const float*)d_in[5];
    const float* w_skip   = (const float*)d_in[6];
    const float* b_skip   = (const float*)d_in[7];

    float* out = (float*)d_out;
    float* out_router = out;                           // 32768*64
    float* out_idx    = out + (size_t)NTOK * E;        // 32768*8
    float* out_skip   = out_idx + (size_t)NTOK * TOPK; // 32768

    int* flags = (int*)d_ws;
    int cap = 0;
    if (ws_size >= 16) {
        size_t c = (ws_size - 8) / 4;
        cap = (c > 65536) ? 65536 : (int)c;
    }

    hipMemsetAsync(d_ws, 0, 8, stream);

    router_kernel<<<dim3(NBLK), dim3(128), 0, stream>>>(
        x, eps, w_router, b_router, w_noise, b_noise, w_skip, b_skip,
        out_router, out_idx, out_skip, flags, cap);

    fixup_kernel<<<dim3(256), dim3(256), 0, stream>>>(
        x, eps, w_router, b_router, w_noise, b_noise,
        out_router, out_idx, flags, cap);
}

// Round 3
// 900.142 us; speedup vs baseline: 1.2038x; 1.2038x over previous
//
#include <hip/hip_runtime.h>
#include <math.h>

// Problem constants
#define NTOK   32768       // B*S = 4*8192
#define D      2048        // N_EMBED
#define E      64          // NUM_EXPERTS
#define TOPK   8
#define NC     128         // 64 router cols + 64 noise cols

// Tiling
#define TM     64          // tokens per block
#define BK     32          // K chunk
#define NBLK   (NTOK / TM) // 512
#define NKC    (D / BK)    // 64
#define BLOCK  256

// LDS layout (floats)
#define XS_OFF    0        // xs[BK][68] transposed x tile (stride 68: 16B-aligned rows, reads conflict-free)
#define XS_STR    68
#define WS_OFF    2176     // ws[BK][140] swizzled: quad q at q*4 + ((q>>3)<<2)  -> 2-way banks (free)
#define WS_STR    140
#define WSK_OFF   6656     // wskip[BK]
#define LG_STR    133      // logits[64][133]: odd stride -> (5t+e)%32 scan is 2-way (free)
#define SP_OFF    8512     // skip partials [4][64]
#define SMEM_FLOATS 8768

// near-tie flag threshold: fp32 worst-case dot error ~2e-5 rms; big margin
#define TIE_EPS 1e-3f

__global__ __launch_bounds__(BLOCK, 2) void router_kernel(
    const float* __restrict__ x, const float* __restrict__ eps,
    const float* __restrict__ w_router, const float* __restrict__ b_router,
    const float* __restrict__ w_noise, const float* __restrict__ b_noise,
    const float* __restrict__ w_skip, const float* __restrict__ b_skip,
    float* __restrict__ out_router, float* __restrict__ out_idx,
    float* __restrict__ out_skip, int* __restrict__ flags, int cap)
{
    __shared__ float smem[SMEM_FLOATS];
    const int tid = threadIdx.x;
    const int tokBase = blockIdx.x * TM;

    // compute-tile mapping: 16 col-groups x 16 token-groups; each thread 4 tok x 8 col
    const int cg = tid & 15;
    const int tg = tid >> 4;
    const int t0 = tg * 4;
    // swizzled ws offsets for column quads 2cg, 2cg+1
    const int qa = 2 * cg;
    const int qb = 2 * cg + 1;
    const int offA = qa * 4 + ((qa >> 3) << 2);
    const int offB = qb * 4 + ((qb >> 3) << 2);

    // skip-gate mapping: 4 quarters x 64 tokens
    const int tS = tid & 63;
    const int quarter = tid >> 6;

    float acc[4][8];
#pragma unroll
    for (int a = 0; a < 4; ++a)
#pragma unroll
        for (int b = 0; b < 8; ++b) acc[a][b] = 0.f;
    float skipAcc = 0.f;

    // prefetch registers for one K chunk
    float4 rx[2];
    float4 rw[4];
    float rwsk;

    auto loadChunk = [&](int kBase) {
#pragma unroll
        for (int r = 0; r < 2; ++r) {
            int g = tid + BLOCK * r;        // 0..511
            int token = g >> 3;             // 0..63
            int q = g & 7;                  // k-quad
            rx[r] = *(const float4*)(x + (size_t)(tokBase + token) * D + kBase + q * 4);
        }
#pragma unroll
        for (int r = 0; r < 4; ++r) {
            int g = tid + BLOCK * r;        // 0..1023
            int kk = g >> 5;                // 0..31
            int cq = g & 31;                // col-quad
            const float* src = (cq < 16)
                ? (w_router + (size_t)(kBase + kk) * E + cq * 4)
                : (w_noise  + (size_t)(kBase + kk) * E + (cq - 16) * 4);
            rw[r] = *(const float4*)src;
        }
        rwsk = w_skip[kBase + (tid & 31)];
    };

    auto storeChunk = [&]() {
#pragma unroll
        for (int r = 0; r < 2; ++r) {
            int g = tid + BLOCK * r;
            int token = g >> 3;
            int q = g & 7;
            smem[XS_OFF + (q * 4 + 0) * XS_STR + token] = rx[r].x;
            smem[XS_OFF + (q * 4 + 1) * XS_STR + token] = rx[r].y;
            smem[XS_OFF + (q * 4 + 2) * XS_STR + token] = rx[r].z;
            smem[XS_OFF + (q * 4 + 3) * XS_STR + token] = rx[r].w;
        }
#pragma unroll
        for (int r = 0; r < 4; ++r) {
            int g = tid + BLOCK * r;
            int kk = g >> 5;
            int cq = g & 31;
            *(float4*)&smem[WS_OFF + kk * WS_STR + cq * 4 + ((cq >> 3) << 2)] = rw[r];
        }
        if (tid < 32) smem[WSK_OFF + tid] = rwsk;
    };

    loadChunk(0);

    for (int kc = 0; kc < NKC; ++kc) {
        __syncthreads();            // previous chunk fully consumed
        storeChunk();
        __syncthreads();

        int kNext = (kc + 1 < NKC) ? (kc + 1) * BK : kc * BK;
        loadChunk(kNext);           // overlap next chunk's global latency with compute

#pragma unroll 4
        for (int kk = 0; kk < BK; ++kk) {
            float4 xa = *(float4*)&smem[XS_OFF + kk * XS_STR + t0];
            float4 wa = *(float4*)&smem[WS_OFF + kk * WS_STR + offA];
            float4 wb = *(float4*)&smem[WS_OFF + kk * WS_STR + offB];
            float xv[4] = {xa.x, xa.y, xa.z, xa.w};
            float wv[8] = {wa.x, wa.y, wa.z, wa.w, wb.x, wb.y, wb.z, wb.w};
#pragma unroll
            for (int a = 0; a < 4; ++a)
#pragma unroll
                for (int b = 0; b < 8; ++b)
                    acc[a][b] = fmaf(xv[a], wv[b], acc[a][b]);
        }

        // skip-gate partial: token tS, k range [quarter*8, quarter*8+8)
#pragma unroll
        for (int kk = 0; kk < 8; ++kk) {
            int k2 = quarter * 8 + kk;
            skipAcc = fmaf(smem[XS_OFF + k2 * XS_STR + tS], smem[WSK_OFF + k2], skipAcc);
        }
    }

    __syncthreads();                // all reads of xs/ws done; smem reusable

    // dump accumulators as logits[t][c], stride 133 (scalar stores, one-time)
#pragma unroll
    for (int a = 0; a < 4; ++a) {
#pragma unroll
        for (int b = 0; b < 8; ++b)
            smem[(t0 + a) * LG_STR + cg * 8 + b] = acc[a][b];
    }
    smem[SP_OFF + quarter * 64 + tS] = skipAcc;
    __syncthreads();

    if (tid < 64) {
        const int t = tid;
        const int tok = tokBase + t;
        float* row = &smem[t * LG_STR];

        // skip gate
        float sv = smem[SP_OFF + t] + smem[SP_OFF + 64 + t]
                 + smem[SP_OFF + 128 + t] + smem[SP_OFF + 192 + t] + b_skip[0];
        out_skip[tok] = 1.f / (1.f + expf(-sv));

        // noisy logits: row[e] <- (router+b) + eps * softplus(noise+b)
#pragma unroll 4
        for (int e4 = 0; e4 < 16; ++e4) {
            float4 ep = *(const float4*)(eps + (size_t)tok * E + e4 * 4);
            float epv[4] = {ep.x, ep.y, ep.z, ep.w};
#pragma unroll
            for (int u = 0; u < 4; ++u) {
                int e = e4 * 4 + u;
                float lg = row[e] + b_router[e];
                float nl = row[64 + e] + b_noise[e];
                float sp = fmaxf(nl, 0.f) + log1pf(expf(-fabsf(nl)));
                row[e] = lg + epv[u] * sp;
            }
        }

        // top-9 (9th value needed for membership-boundary gap check)
        float vals[9];
        int idxs[8];
        for (int p = 0; p < 9; ++p) {
            float best = -INFINITY;
            int bi = 0;
            for (int e = 0; e < 64; ++e) {
                float v = row[e];
                if (v > best) { best = v; bi = e; }
            }
            vals[p] = best;
            if (p < 8) idxs[p] = bi;
            row[bi] = -INFINITY;
        }

        // flag near-ties at any boundary affecting top-8 content/order
        float mg = 1e30f;
#pragma unroll
        for (int p = 0; p < 8; ++p) mg = fminf(mg, vals[p] - vals[p + 1]);
        if (mg < TIE_EPS) {
            int slot = atomicAdd(flags, 1);
            if (slot < cap) flags[2 + slot] = tok;
        }

        float m = vals[0];
        float g[8];
        float s = 0.f;
#pragma unroll
        for (int p = 0; p < 8; ++p) { g[p] = expf(vals[p] - m); s += g[p]; }
        float inv = 1.f / s;

        // scatter gates into a zeroed scratch region of the row, then store
        float* rrow = row + 64;
#pragma unroll
        for (int e = 0; e < 64; ++e) rrow[e] = 0.f;
#pragma unroll
        for (int p = 0; p < 8; ++p) rrow[idxs[p]] = g[p] * inv;
#pragma unroll
        for (int e4 = 0; e4 < 16; ++e4) {
            float4 o = make_float4(rrow[e4 * 4], rrow[e4 * 4 + 1],
                                   rrow[e4 * 4 + 2], rrow[e4 * 4 + 3]);
            *(float4*)(out_router + (size_t)tok * E + e4 * 4) = o;
        }

        float4 i0 = make_float4((float)idxs[0], (float)idxs[1], (float)idxs[2], (float)idxs[3]);
        float4 i1 = make_float4((float)idxs[4], (float)idxs[5], (float)idxs[6], (float)idxs[7]);
        *(float4*)(out_idx + (size_t)tok * TOPK)     = i0;
        *(float4*)(out_idx + (size_t)tok * TOPK + 4) = i1;
    }
}

// f64 recompute for near-tie tokens.
// One WAVE per token: lane = expert, each lane computes BOTH router & noise dots
// with 8 independent f64 partials (ILP); w loads coalesce across lanes.
__global__ __launch_bounds__(256) void fixup_kernel(
    const float* __restrict__ x, const float* __restrict__ eps,
    const float* __restrict__ w_router, const float* __restrict__ b_router,
    const float* __restrict__ w_noise, const float* __restrict__ b_noise,
    float* __restrict__ out_router, float* __restrict__ out_idx,
    const int* __restrict__ flags, int cap)
{
    __shared__ double sm[4][64];
    const int tid  = threadIdx.x;
    const int lane = tid & 63;      // expert
    const int sub  = tid >> 6;      // wave within block

    int count = flags[0];
    if (count > cap) count = cap;

    for (int i = blockIdx.x * 4 + sub; i < count; i += gridDim.x * 4) {
        int tok = flags[2 + i];
        const float* xr = x + (size_t)tok * D;

        double pr0 = 0, pr1 = 0, pr2 = 0, pr3 = 0;
        double pn0 = 0, pn1 = 0, pn2 = 0, pn3 = 0;
        for (int k = 0; k < D; k += 4) {
            float4 xv = *(const float4*)(xr + k);
            pr0 += (double)xv.x * (double)w_router[(size_t)(k + 0) * E + lane];
            pr1 += (double)xv.y * (double)w_router[(size_t)(k + 1) * E + lane];
            pr2 += (double)xv.z * (double)w_router[(size_t)(k + 2) * E + lane];
            pr3 += (double)xv.w * (double)w_router[(size_t)(k + 3) * E + lane];
            pn0 += (double)xv.x * (double)w_noise[(size_t)(k + 0) * E + lane];
            pn1 += (double)xv.y * (double)w_noise[(size_t)(k + 1) * E + lane];
            pn2 += (double)xv.z * (double)w_noise[(size_t)(k + 2) * E + lane];
            pn3 += (double)xv.w * (double)w_noise[(size_t)(k + 3) * E + lane];
        }
        double lg = (pr0 + pr1) + (pr2 + pr3) + (double)b_router[lane];
        double nl = (pn0 + pn1) + (pn2 + pn3) + (double)b_noise[lane];
        double sp = fmax(nl, 0.0) + log1p(exp(-fabs(nl)));
        sm[sub][lane] = lg + (double)eps[(size_t)tok * E + lane] * sp;
        // wave-internal LDS write->read: compiler inserts lgkmcnt wait; no barrier
        // needed across waves (each wave owns sm[sub]).
        __builtin_amdgcn_wave_barrier();

        if (lane == 0) {
            double tmp[64];
            for (int j = 0; j < 64; ++j) tmp[j] = sm[sub][j];
            double vals[8]; int idxs[8];
            for (int p = 0; p < 8; ++p) {
                double best = -1e300; int bi = 0;
                for (int j = 0; j < 64; ++j)
                    if (tmp[j] > best) { best = tmp[j]; bi = j; }
                vals[p] = best; idxs[p] = bi; tmp[bi] = -1e300;
            }
            double mx = vals[0], s = 0.0, g[8];
            for (int p = 0; p < 8; ++p) { g[p] = exp(vals[p] - mx); s += g[p]; }
            float rowv[64];
            for (int j = 0; j < 64; ++j) rowv[j] = 0.f;
            for (int p = 0; p < 8; ++p) rowv[idxs[p]] = (float)(g[p] / s);
            for (int j = 0; j < 64; ++j) out_router[(size_t)tok * E + j] = rowv[j];
            for (int p = 0; p < 8; ++p) out_idx[(size_t)tok * TOPK + p] = (float)idxs[p];
        }
        __builtin_amdgcn_wave_barrier();
    }
}

extern "C" void kernel_launch(void* const* d_in, const int* in_sizes, int n_in,
                              void* d_out, int out_size, void* d_ws, size_t ws_size,
                              hipStream_t stream) {
    const float* x        = (const float*)d_in[0];
    const float* eps      = (const float*)d_in[1];
    const float* w_router = (const float*)d_in[2];
    const float* b_router = (const float*)d_in[3];
    const float* w_noise  = (const float*)d_in[4];
    const float* b_noise  = (const float*)d_in[5];
    const float* w_skip   = (const float*)d_in[6];
    const float* b_skip   = (const float*)d_in[7];

    float* out = (float*)d_out;
    float* out_router = out;                           // 32768*64
    float* out_idx    = out + (size_t)NTOK * E;        // 32768*8
    float* out_skip   = out_idx + (size_t)NTOK * TOPK; // 32768

    int* flags = (int*)d_ws;
    int cap = 0;
    if (ws_size >= 16) {
        size_t c = (ws_size - 8) / 4;
        cap = (c > 65536) ? 65536 : (int)c;
    }

    hipMemsetAsync(d_ws, 0, 8, stream);

    router_kernel<<<dim3(NBLK), dim3(BLOCK), 0, stream>>>(
        x, eps, w_router, b_router, w_noise, b_noise, w_skip, b_skip,
        out_router, out_idx, out_skip, flags, cap);

    fixup_kernel<<<dim3(256), dim3(256), 0, stream>>>(
        x, eps, w_router, b_router, w_noise, b_noise,
        out_router, out_idx, flags, cap);
}

// Round 4
// 543.640 us; speedup vs baseline: 1.9932x; 1.6558x over previous
//
#include <hip/hip_runtime.h>
#include <math.h>

// Problem constants
#define NTOK   32768       // B*S
#define D      2048        // N_EMBED
#define E      64          // NUM_EXPERTS
#define TOPK   8

#define BLOCK  256
#define TM     64          // tokens per block
#define BK     32          // K per chunk == MFMA K
#define NCHUNK (D / BK)    // 64
#define NBLK   (NTOK / TM) // 512

// w_bf layout in d_ws: per chunk c (16384 B): hi frags [0,8192), lo frags [8192,16384)
// frag index = koct*128 + col (col 0..63 router, 64..127 noise), 16 B each, elem j at +2j
#define WBF_BYTES (NCHUNK * 16384)   // 1 MiB

// LDS layout (bytes), double-buffered A/B
#define BUF_STRIDE 24576
// buf b: A hi @ b*24576, A lo @ +4096, B hi @ +8192, B lo @ +16384
#define WSK_OFF 49152      // float[2048] staged w_skip
#define SP_OFF  57344      // float[64] skip partials
#define SMEM_BYTES 57600
// logits (epilogue) reuse bytes [0, 34048): float[64][133]
#define LG_STR 133

#define TIE_EPS 2e-4f

typedef __bf16 bf16x8 __attribute__((ext_vector_type(8)));
typedef float  f32x4  __attribute__((ext_vector_type(4)));

#define AS1 __attribute__((address_space(1)))
#define AS3 __attribute__((address_space(3)))

__device__ __forceinline__ unsigned short f2bf_rne(float f) {
    unsigned int u = __float_as_uint(f);
    u += 0x7FFFu + ((u >> 16) & 1u);
    return (unsigned short)(u >> 16);
}

__device__ __forceinline__ void split_pack8(const float* xv, uint4& hv, uint4& lv) {
    unsigned int h[8], l[8];
#pragma unroll
    for (int j = 0; j < 8; ++j) {
        unsigned short hb = f2bf_rne(xv[j]);
        float hf = __uint_as_float(((unsigned int)hb) << 16);
        unsigned short lb = f2bf_rne(xv[j] - hf);
        h[j] = hb; l[j] = lb;
    }
    hv.x = h[0] | (h[1] << 16); hv.y = h[2] | (h[3] << 16);
    hv.z = h[4] | (h[5] << 16); hv.w = h[6] | (h[7] << 16);
    lv.x = l[0] | (l[1] << 16); lv.y = l[2] | (l[3] << 16);
    lv.z = l[4] | (l[5] << 16); lv.w = l[6] | (l[7] << 16);
}

// ---------------- pre-kernel: convert W (router||noise) to split-bf16 fragment layout ----------
__global__ __launch_bounds__(256) void convert_w_kernel(
    const float* __restrict__ wr, const float* __restrict__ wn, char* __restrict__ wbf)
{
    int u = blockIdx.x * 256 + threadIdx.x;      // 0..32767 = 64 chunks * 4 koct * 128 col
    int col  = u & 127;
    int koct = (u >> 7) & 3;
    int c    = u >> 9;
    const float* src = (col < 64)
        ? (wr + (size_t)(c * BK + koct * 8) * E + col)
        : (wn + (size_t)(c * BK + koct * 8) * E + (col - 64));
    float xv[8];
#pragma unroll
    for (int j = 0; j < 8; ++j) xv[j] = src[(size_t)j * E];
    uint4 hv, lv;
    split_pack8(xv, hv, lv);
    char* dst = wbf + (size_t)c * 16384 + (size_t)(koct * 128 + col) * 16;
    *(uint4*)dst = hv;
    *(uint4*)(dst + 8192) = lv;
}

// ---------------- main router kernel: split-bf16 MFMA GEMM + epilogue --------------------------
__global__ __launch_bounds__(BLOCK, 2) void router_kernel(
    const float* __restrict__ x, const float* __restrict__ eps,
    const char* __restrict__ wbf,
    const float* __restrict__ b_router, const float* __restrict__ b_noise,
    const float* __restrict__ w_skip, const float* __restrict__ b_skip,
    float* __restrict__ out_router, float* __restrict__ out_idx,
    float* __restrict__ out_skip, int* __restrict__ flags, int cap)
{
    __shared__ __attribute__((aligned(16))) char smem[SMEM_BYTES];
    const int tid = threadIdx.x;
    const int tokBase = blockIdx.x * TM;

    const int lane = tid & 63;
    const int wv   = __builtin_amdgcn_readfirstlane(tid >> 6);  // wave id 0..3
    const int q    = lane >> 4;      // k-octet within chunk for frag reads
    const int m    = lane & 15;

    // A-staging mapping: thread -> (token, koct); coalesced x loads (4 lanes = 32B contig per token)
    const int tokA  = tid >> 2;      // 0..63
    const int koctA = tid & 3;       // 0..3
    const int fragA = (koctA << 6) + (tokA ^ (koctA << 2));   // XOR swizzle: store conflict-free
    const float* xptr = x + (size_t)(tokBase + tokA) * D + koctA * 8;

    f32x4 acc[4][2];
#pragma unroll
    for (int tt = 0; tt < 4; ++tt)
#pragma unroll
        for (int cw = 0; cw < 2; ++cw) acc[tt][cw] = (f32x4){0.f, 0.f, 0.f, 0.f};
    float skipAcc = 0.f;

    float* wsk = (float*)(smem + WSK_OFF);

    auto issueB = [&](int c, int buf) {
        const char* src = wbf + (size_t)c * 16384;
        char* dstbase = smem + buf * BUF_STRIDE + 8192;
#pragma unroll
        for (int r = 0; r < 4; ++r) {
            int seg = r * 4 + wv;   // 16 segments of 1 KiB cover hi+lo 16 KiB
            __builtin_amdgcn_global_load_lds(
                (const AS1 unsigned int*)(src + seg * 1024 + lane * 16),
                (AS3 unsigned int*)(dstbase + seg * 1024), 16, 0, 0);
        }
    };

    auto storeA = [&](int buf, float4 a0, float4 a1) {
        float xv[8] = {a0.x, a0.y, a0.z, a0.w, a1.x, a1.y, a1.z, a1.w};
        uint4 hv, lv;
        split_pack8(xv, hv, lv);
        char* ab = smem + buf * BUF_STRIDE;
        *(uint4*)(ab + fragA * 16) = hv;
        *(uint4*)(ab + 4096 + fragA * 16) = lv;
    };

    auto skipFma = [&](float4 a0, float4 a1, int c) {
        const float* wk = wsk + c * BK + koctA * 8;
        skipAcc = fmaf(a0.x, wk[0], skipAcc); skipAcc = fmaf(a0.y, wk[1], skipAcc);
        skipAcc = fmaf(a0.z, wk[2], skipAcc); skipAcc = fmaf(a0.w, wk[3], skipAcc);
        skipAcc = fmaf(a1.x, wk[4], skipAcc); skipAcc = fmaf(a1.y, wk[5], skipAcc);
        skipAcc = fmaf(a1.z, wk[6], skipAcc); skipAcc = fmaf(a1.w, wk[7], skipAcc);
    };

    auto compute = [&](int buf) {
        const char* ab = smem + buf * BUF_STRIDE;
        const char* bb = ab + 8192;
        uint4 ah[4], al[4], bh[2], bl[2];
#pragma unroll
        for (int tt = 0; tt < 4; ++tt) {
            int f = (q << 6) + (((tt << 4) + m) ^ (q << 2));
            ah[tt] = *(const uint4*)(ab + f * 16);
            al[tt] = *(const uint4*)(ab + 4096 + f * 16);
        }
#pragma unroll
        for (int cw = 0; cw < 2; ++cw) {
            int f = (q << 7) + (wv << 5) + (cw << 4) + m;
            bh[cw] = *(const uint4*)(bb + f * 16);
            bl[cw] = *(const uint4*)(bb + 8192 + f * 16);
        }
#pragma unroll
        for (int tt = 0; tt < 4; ++tt)
#pragma unroll
            for (int cw = 0; cw < 2; ++cw) {
                bf16x8 Ah = __builtin_bit_cast(bf16x8, ah[tt]);
                bf16x8 Al = __builtin_bit_cast(bf16x8, al[tt]);
                bf16x8 Bh = __builtin_bit_cast(bf16x8, bh[cw]);
                bf16x8 Bl = __builtin_bit_cast(bf16x8, bl[cw]);
                acc[tt][cw] = __builtin_amdgcn_mfma_f32_16x16x32_bf16(Ah, Bh, acc[tt][cw], 0, 0, 0);
                acc[tt][cw] = __builtin_amdgcn_mfma_f32_16x16x32_bf16(Ah, Bl, acc[tt][cw], 0, 0, 0);
                acc[tt][cw] = __builtin_amdgcn_mfma_f32_16x16x32_bf16(Al, Bh, acc[tt][cw], 0, 0, 0);
            }
    };

    // ---- prologue: stage w_skip, chunk 0 ----
#pragma unroll
    for (int r = 0; r < 2; ++r) {
        int i4 = tid + 256 * r;          // float4 index 0..511
        ((float4*)wsk)[i4] = ((const float4*)w_skip)[i4];
    }
    float4 ra0 = *(const float4*)(xptr);
    float4 ra1 = *(const float4*)(xptr + 4);
    issueB(0, 0);
    storeA(0, ra0, ra1);
    __syncthreads();
    skipFma(ra0, ra1, 0);

    // ---- K loop, double-buffered ----
    for (int c = 0; c < NCHUNK; ++c) {
        int cur = c & 1;
        float4 rb0, rb1;
        if (c + 1 < NCHUNK) {
            rb0 = *(const float4*)(xptr + (c + 1) * BK);
            rb1 = *(const float4*)(xptr + (c + 1) * BK + 4);
            issueB(c + 1, cur ^ 1);
        }
        compute(cur);
        if (c + 1 < NCHUNK) {
            storeA(cur ^ 1, rb0, rb1);
            skipFma(rb0, rb1, c + 1);
        }
        __syncthreads();
    }

    // ---- dump accumulators to logits[64][133] (C/D: col=lane&15, row=q*4+reg) ----
    float* lg = (float*)smem;
#pragma unroll
    for (int tt = 0; tt < 4; ++tt)
#pragma unroll
        for (int cw = 0; cw < 2; ++cw) {
#pragma unroll
            for (int reg = 0; reg < 4; ++reg) {
                int token = tt * 16 + q * 4 + reg;
                int col = wv * 32 + cw * 16 + m;
                lg[token * LG_STR + col] = acc[tt][cw][reg];
            }
        }

    // skip reduce: threads 4t..4t+3 hold token t partials
    skipAcc += __shfl_xor(skipAcc, 1);
    skipAcc += __shfl_xor(skipAcc, 2);
    if ((tid & 3) == 0) ((float*)(smem + SP_OFF))[tokA] = skipAcc;
    __syncthreads();

    // ---- epilogue: wave 0, one lane per token ----
    if (tid < 64) {
        const int t = tid;
        const int tok = tokBase + t;
        float* row = lg + t * LG_STR;

        float sv = ((float*)(smem + SP_OFF))[t] + b_skip[0];
        out_skip[tok] = 1.f / (1.f + expf(-sv));

        const float4* epsr = (const float4*)(eps + (size_t)tok * E);
#pragma unroll 4
        for (int e4 = 0; e4 < 16; ++e4) {
            float4 ep = epsr[e4];
            float epv[4] = {ep.x, ep.y, ep.z, ep.w};
#pragma unroll
            for (int u2 = 0; u2 < 4; ++u2) {
                int e = e4 * 4 + u2;
                float lgv = row[e] + b_router[e];
                float nl  = row[64 + e] + b_noise[e];
                float sp  = fmaxf(nl, 0.f) + log1pf(expf(-fabsf(nl)));
                row[e] = lgv + epv[u2] * sp;
            }
        }

        // top-9 (strict '>' => lowest index wins ties; descending values, matches lax.top_k)
        float vals[9];
        int idxs[8];
        for (int p = 0; p < 9; ++p) {
            float best = -INFINITY;
            int bi = 0;
            for (int e = 0; e < 64; ++e) {
                float v = row[e];
                if (v > best) { best = v; bi = e; }
            }
            vals[p] = best;
            if (p < 8) idxs[p] = bi;
            row[bi] = -INFINITY;
        }

        float mg = 1e30f;
#pragma unroll
        for (int p = 0; p < 8; ++p) mg = fminf(mg, vals[p] - vals[p + 1]);
        if (mg < TIE_EPS) {
            int slot = atomicAdd(flags, 1);
            if (slot < cap) flags[2 + slot] = tok;
        }

        float mx = vals[0];
        float g[8], s = 0.f;
#pragma unroll
        for (int p = 0; p < 8; ++p) { g[p] = expf(vals[p] - mx); s += g[p]; }
        float inv = 1.f / s;

        float* rrow = row + 64;
#pragma unroll
        for (int e = 0; e < 64; ++e) rrow[e] = 0.f;
#pragma unroll
        for (int p = 0; p < 8; ++p) rrow[idxs[p]] = g[p] * inv;
#pragma unroll
        for (int e4 = 0; e4 < 16; ++e4) {
            float4 o = make_float4(rrow[e4 * 4], rrow[e4 * 4 + 1],
                                   rrow[e4 * 4 + 2], rrow[e4 * 4 + 3]);
            *(float4*)(out_router + (size_t)tok * E + e4 * 4) = o;
        }
        float4 i0 = make_float4((float)idxs[0], (float)idxs[1], (float)idxs[2], (float)idxs[3]);
        float4 i1 = make_float4((float)idxs[4], (float)idxs[5], (float)idxs[6], (float)idxs[7]);
        *(float4*)(out_idx + (size_t)tok * TOPK)     = i0;
        *(float4*)(out_idx + (size_t)tok * TOPK + 4) = i1;
    }
}

// ---------------- f64 fixup: one block per token, 4 waves split K, lane = expert ---------------
__global__ __launch_bounds__(256) void fixup_kernel(
    const float* __restrict__ x, const float* __restrict__ eps,
    const float* __restrict__ w_router, const float* __restrict__ b_router,
    const float* __restrict__ w_noise, const float* __restrict__ b_noise,
    float* __restrict__ out_router, float* __restrict__ out_idx,
    const int* __restrict__ flags, int cap)
{
    __shared__ double smR[4][64];
    __shared__ double smN[4][64];
    __shared__ double noisy[64];
    const int tid  = threadIdx.x;
    const int lane = tid & 63;      // expert
    const int qw   = tid >> 6;      // K quarter

    int count = flags[0];
    if (count > cap) count = cap;

    for (int i = blockIdx.x; i < count; i += gridDim.x) {
        int tok = flags[2 + i];
        const float4* xr4 = (const float4*)(x + (size_t)tok * D + qw * 512);
        const float* wrB = w_router + (size_t)(qw * 512) * E + lane;
        const float* wnB = w_noise  + (size_t)(qw * 512) * E + lane;

        double pr0 = 0, pr1 = 0, pr2 = 0, pr3 = 0;
        double pn0 = 0, pn1 = 0, pn2 = 0, pn3 = 0;
        for (int it = 0; it < 128; ++it) {
            float4 xv = xr4[it];
            const float* wr = wrB + (size_t)(it * 4) * E;
            const float* wn = wnB + (size_t)(it * 4) * E;
            pr0 += (double)xv.x * (double)wr[0];
            pr1 += (double)xv.y * (double)wr[E];
            pr2 += (double)xv.z * (double)wr[2 * E];
            pr3 += (double)xv.w * (double)wr[3 * E];
            pn0 += (double)xv.x * (double)wn[0];
            pn1 += (double)xv.y * (double)wn[E];
            pn2 += (double)xv.z * (double)wn[2 * E];
            pn3 += (double)xv.w * (double)wn[3 * E];
        }
        smR[qw][lane] = (pr0 + pr1) + (pr2 + pr3);
        smN[qw][lane] = (pn0 + pn1) + (pn2 + pn3);
        __syncthreads();

        if (tid < 64) {
            double lgv = smR[0][tid] + smR[1][tid] + smR[2][tid] + smR[3][tid] + (double)b_router[tid];
            double nl  = smN[0][tid] + smN[1][tid] + smN[2][tid] + smN[3][tid] + (double)b_noise[tid];
            double sp  = fmax(nl, 0.0) + log1p(exp(-fabs(nl)));
            noisy[tid] = lgv + (double)eps[(size_t)tok * E + tid] * sp;
        }
        __syncthreads();

        if (tid == 0) {
            double tmp[64];
            for (int j = 0; j < 64; ++j) tmp[j] = noisy[j];
            double vals[8]; int idxs[8];
            for (int p = 0; p < 8; ++p) {
                double best = -1e300; int bi = 0;
                for (int j = 0; j < 64; ++j)
                    if (tmp[j] > best) { best = tmp[j]; bi = j; }
                vals[p] = best; idxs[p] = bi; tmp[bi] = -1e300;
            }
            double mx = vals[0], s = 0.0, g[8];
            for (int p = 0; p < 8; ++p) { g[p] = exp(vals[p] - mx); s += g[p]; }
            float rowv[64];
            for (int j = 0; j < 64; ++j) rowv[j] = 0.f;
            for (int p = 0; p < 8; ++p) rowv[idxs[p]] = (float)(g[p] / s);
            for (int j = 0; j < 64; ++j) out_router[(size_t)tok * E + j] = rowv[j];
            for (int p = 0; p < 8; ++p) out_idx[(size_t)tok * TOPK + p] = (float)idxs[p];
        }
        __syncthreads();
    }
}

extern "C" void kernel_launch(void* const* d_in, const int* in_sizes, int n_in,
                              void* d_out, int out_size, void* d_ws, size_t ws_size,
                              hipStream_t stream) {
    const float* x        = (const float*)d_in[0];
    const float* eps      = (const float*)d_in[1];
    const float* w_router = (const float*)d_in[2];
    const float* b_router = (const float*)d_in[3];
    const float* w_noise  = (const float*)d_in[4];
    const float* b_noise  = (const float*)d_in[5];
    const float* w_skip   = (const float*)d_in[6];
    const float* b_skip   = (const float*)d_in[7];

    float* out = (float*)d_out;
    float* out_router = out;                           // 32768*64
    float* out_idx    = out + (size_t)NTOK * E;        // 32768*8
    float* out_skip   = out_idx + (size_t)NTOK * TOPK; // 32768

    char* wbf  = (char*)d_ws;
    int* flags = (int*)((char*)d_ws + WBF_BYTES);
    int cap = 0;
    if (ws_size > WBF_BYTES + 16) {
        size_t c = (ws_size - WBF_BYTES - 8) / 4;
        cap = (c > 16384) ? 16384 : (int)c;
    }

    hipMemsetAsync((char*)d_ws + WBF_BYTES, 0, 8, stream);

    convert_w_kernel<<<dim3(128), dim3(256), 0, stream>>>(w_router, w_noise, wbf);

    router_kernel<<<dim3(NBLK), dim3(BLOCK), 0, stream>>>(
        x, eps, wbf, b_router, b_noise, w_skip, b_skip,
        out_router, out_idx, out_skip, flags, cap);

    fixup_kernel<<<dim3(512), dim3(256), 0, stream>>>(
        x, eps, w_router, b_router, w_noise, b_noise,
        out_router, out_idx, flags, cap);
}